// Round 15
// baseline (177.467 us; speedup 1.0000x reference)
//
#include <hip/hip_runtime.h>

#define B_ 2
#define S_ 2048
#define D_ 1024
#define H_ 16
#define HD_ 64
#define M_ (B_*S_)

typedef __attribute__((ext_vector_type(8))) short bf16x8;
typedef __attribute__((ext_vector_type(4))) short s16x4;
typedef __attribute__((ext_vector_type(4))) float f32x4;
typedef __attribute__((ext_vector_type(4))) unsigned int u32x4;

static __device__ __forceinline__ unsigned short f2bf(float f) {
  unsigned int u = __builtin_bit_cast(unsigned int, f);
  u += 0x7FFFu + ((u >> 16) & 1u);   // RNE
  return (unsigned short)(u >> 16);
}

static __device__ __forceinline__ unsigned int cvt_pk_bf16(float a, float b) {
  unsigned int r;
  asm("v_cvt_pk_bf16_f32 %0, %1, %2" : "=v"(r) : "v"(a), "v"(b));
  return r;   // lo = bf16(a), hi = bf16(b)
}

static __device__ __forceinline__ void gload_lds16(const void* g, void* l) {
  __builtin_amdgcn_global_load_lds(
      (const __attribute__((address_space(1))) unsigned int*)g,
      (__attribute__((address_space(3))) unsigned int*)l, 16, 0, 0);
}

// ---------- K0a: x fp32 -> bf16 ----------
__global__ __launch_bounds__(256) void xcvt_kernel(const float* __restrict__ x,
                                                   unsigned short* __restrict__ xb) {
  size_t i = ((size_t)blockIdx.x * 256 + threadIdx.x) * 8;
  float4 a = ((const float4*)(x + i))[0];
  float4 b = ((const float4*)(x + i))[1];
  bf16x8 w;
  w[0]=(short)f2bf(a.x); w[1]=(short)f2bf(a.y); w[2]=(short)f2bf(a.z); w[3]=(short)f2bf(a.w);
  w[4]=(short)f2bf(b.x); w[5]=(short)f2bf(b.y); w[6]=(short)f2bf(b.z); w[7]=(short)f2bf(b.w);
  *(bf16x8*)(xb + i) = w;
}

// ---------- K0b: transpose + convert weights: Wt[z][n][k] = bf16(W_z[k][n]) ----------
__global__ void wtrans_kernel(const float* __restrict__ Wq, const float* __restrict__ Wk,
                              const float* __restrict__ Wv, const float* __restrict__ Wo,
                              unsigned short* __restrict__ wt) {
  __shared__ float tile[32][33];
  const float* W = blockIdx.z==0 ? Wq : blockIdx.z==1 ? Wk : blockIdx.z==2 ? Wv : Wo;
  unsigned short* out = wt + (size_t)blockIdx.z * D_ * D_;
  int n0 = blockIdx.x*32, k0 = blockIdx.y*32;
  int tx = threadIdx.x, ty = threadIdx.y;   // 32 x 8
  #pragma unroll
  for (int i=0;i<4;i++) tile[ty+i*8][tx] = W[(size_t)(k0+ty+i*8)*D_ + n0+tx];
  __syncthreads();
  #pragma unroll
  for (int i=0;i<4;i++) out[(size_t)(n0+ty+i*8)*D_ + (k0+tx)] = f2bf(tile[tx][ty+i*8]);
}

// ---------- shared GEMM tile body (m97 structure, BK=64, XOR-swizzled LDS) ----------
#define GEMM_K_LOOP(Abase, Bbase)                                                     \
  for (int ks = 0; ks < 16; ++ks) {                                                   \
    const int k0 = ks * 64;                                                           \
    __syncthreads();                                                                  \
    _Pragma("unroll")                                                                 \
    for (int p = 0; p < 4; ++p) {                                                     \
      int c = p*256 + t;                                                              \
      int row = c >> 3, sl = (c & 7) ^ (row & 7);                                     \
      gload_lds16(Abase + (size_t)row*D_ + k0 + sl*8, &As[(p*256 + wid*64)*8]);       \
    }                                                                                 \
    _Pragma("unroll")                                                                 \
    for (int p = 0; p < 4; ++p) {                                                     \
      int c = p*256 + t;                                                              \
      int row = c >> 3, sl = (c & 7) ^ (row & 7);                                     \
      gload_lds16(Bbase + (size_t)row*D_ + k0 + sl*8, &Bs[(p*256 + wid*64)*8]);       \
    }                                                                                 \
    __syncthreads();                                                                  \
    _Pragma("unroll")                                                                 \
    for (int kk = 0; kk < 2; ++kk) {                                                  \
      bf16x8 af[4], bfr[4];                                                           \
      _Pragma("unroll")                                                               \
      for (int m = 0; m < 4; ++m) {                                                   \
        int row = wr + m*16 + l15;                                                    \
        af[m] = *(const bf16x8*)((const char*)As + row*128 + (((kk*4+lg)^(row&7))<<4)); \
      }                                                                               \
      _Pragma("unroll")                                                               \
      for (int n = 0; n < 4; ++n) {                                                   \
        int row = wc + n*16 + l15;                                                    \
        bfr[n] = *(const bf16x8*)((const char*)Bs + row*128 + (((kk*4+lg)^(row&7))<<4)); \
      }                                                                               \
      _Pragma("unroll")                                                               \
      for (int m = 0; m < 4; ++m)                                                     \
        _Pragma("unroll")                                                             \
        for (int n = 0; n < 4; ++n)                                                   \
          acc[m][n] = __builtin_amdgcn_mfma_f32_16x16x32_bf16(af[m], bfr[n], acc[m][n], 0,0,0); \
    }                                                                                 \
  }

// ---------- K1: QKV projection GEMM (bf16 x bf16) ----------
// Q is pre-scaled by log2(e)/8 so attention can use exp2(score) directly.
__global__ __launch_bounds__(256,3) void gemm_qkv_kernel(
    const unsigned short* __restrict__ xb, const unsigned short* __restrict__ wt,
    unsigned short* __restrict__ Qo, unsigned short* __restrict__ Ko,
    unsigned short* __restrict__ Vto) {
  __shared__ __align__(16) unsigned short As[128*64];
  __shared__ __align__(16) unsigned short Bs[128*64];
  const int z = blockIdx.z;
  const int m0 = blockIdx.y*128, n0 = blockIdx.x*128;
  const int t = threadIdx.x, lane = t & 63, wid = t >> 6;
  const int wr = (wid>>1)*64, wc = (wid&1)*64;
  const int l15 = lane & 15, lg = lane >> 4;
  const unsigned short* Ab = xb + (size_t)m0 * D_;
  const unsigned short* Bb = wt + (size_t)z * D_ * D_ + (size_t)n0 * D_;

  f32x4 acc[4][4];
  #pragma unroll
  for (int m=0;m<4;m++)
    #pragma unroll
    for (int n=0;n<4;n++) acc[m][n] = f32x4{0.f,0.f,0.f,0.f};

  GEMM_K_LOOP(Ab, Bb)

  const float qscale = 0.18033688011112042f;  // log2(e)/8
  #pragma unroll
  for (int m=0;m<4;m++) {
    #pragma unroll
    for (int n=0;n<4;n++) {
      #pragma unroll
      for (int r=0;r<4;r++) {
        int gm = m0 + wr + m*16 + lg*4 + r;
        int gn = n0 + wc + n*16 + l15;
        int b = gm >> 11, s = gm & (S_-1);
        int h = gn >> 6,  d = gn & 63;
        float av = acc[m][n][r];
        if (z==0) av *= qscale;
        unsigned short val = f2bf(av);
        if (z==0)      Qo[(((size_t)(b*H_+h))*S_ + s)*HD_ + d] = val;
        else if (z==1) Ko[(((size_t)(b*H_+h))*S_ + s)*HD_ + d] = val;
        else           Vto[(((size_t)(b*H_+h))*HD_ + d)*S_ + s] = val;
      }
    }
  }
}

// ---------- K2: causal flash attention v13 (barrier-free, counted vmcnt) ----------
// Key-split (v12): wave w owns keys [w*16, w*16+16) of each 64-key chunk, over all
// 64 q-rows; additive merge once at end. NEW: each wave stages its OWN K rows AND
// its own V slice (Vt[all 64 d][wave's 16 keys], per-lane source, ks-XOR 2-way
// layout) -> every wave reads only LDS it wrote -> NO per-chunk __syncthreads.
// Pipeline = 2-deep counted vmcnt(4) (T4): next chunk's loads stay in flight
// across this chunk's compute; lgkmcnt(0)+sched_barrier before buffer reuse.
__global__ __launch_bounds__(256,4) void attn_kernel(
    const unsigned short* __restrict__ Q, const unsigned short* __restrict__ K,
    const unsigned short* __restrict__ Vt, unsigned short* __restrict__ ctx) {
  __shared__ __align__(16) unsigned short SMEM[4][4096];  // per wave: K[2][1024] + V[2][1024] ushorts
  __shared__ float LS[2][64];
  const int t = threadIdx.x, lane = t & 63, wid = t >> 6;
  const int bh = blockIdx.x & 31;
  const int qt = 31 - (int)(blockIdx.x >> 5);   // heavy tiles first
  const int b = bh >> 4, h = bh & 15;
  const int q0 = qt * 64;
  const int nchunk = qt + 1;
  const unsigned short* Qp = Q  + (size_t)bh * S_ * HD_;
  const unsigned short* Kp = K  + (size_t)bh * S_ * HD_;
  const unsigned short* Vp = Vt + (size_t)bh * HD_ * S_;
  const int l15 = lane & 15, lg = lane >> 4;
  const int rsub = lane >> 3, slot = lane & 7;
  const int sslot = slot ^ rsub;                // K source pre-swizzle (row&7 == rsub)

  unsigned short* kbase = &SMEM[wid][0];        // 2 bufs x 1024 ushorts
  unsigned short* vbase = &SMEM[wid][2048];     // 2 bufs x 1024 ushorts

  // Q fragments for ALL 4 q-tiles (B-operand)
  bf16x8 qf0[4], qf1[4];
  #pragma unroll
  for (int j=0;j<4;j++) {
    qf0[j] = *(const bf16x8*)(Qp + (size_t)(q0 + j*16 + l15)*HD_ + lg*8);
    qf1[j] = *(const bf16x8*)(Qp + (size_t)(q0 + j*16 + l15)*HD_ + 32 + lg*8);
  }

  f32x4 o[4][4];      // [q-tile j][d-tile dt]
  f32x4 accl[4];      // [q-tile j]
  #pragma unroll
  for (int j=0;j<4;j++) {
    accl[j] = f32x4{0.f,0.f,0.f,0.f};
    #pragma unroll
    for (int dt=0;dt<4;dt++) o[j][dt] = f32x4{0.f,0.f,0.f,0.f};
  }
  s16x4 ones;
  ones[0] = (short)0x3F80; ones[1] = (short)0x3F80;
  ones[2] = (short)0x3F80; ones[3] = (short)0x3F80;

  // staging sources (bumped by constants each chunk)
  const unsigned short* kS0 = Kp + (size_t)(16*wid + rsub)*HD_ + sslot*8;
  const unsigned short* kS1 = kS0 + 8*HD_;
  const int vrow32 = lane >> 1;                           // 0..31
  const int vks = (lane & 1) ^ ((lane >> 2) & 1);         // ks-XOR (2-way banks)
  const unsigned short* vS0 = Vp + (size_t)vrow32*S_ + 16*wid + vks*8;
  const unsigned short* vS1 = vS0 + (size_t)32*S_;

  auto stage = [&](int buf) {
    unsigned short* kd = kbase + buf*1024;
    unsigned short* vd = vbase + buf*1024;
    gload_lds16(kS0, kd);
    gload_lds16(kS1, kd + 512);
    gload_lds16(vS0, vd);        // d = 0..31  (lane>>1), keys 16w + vks*8..+8
    gload_lds16(vS1, vd + 512);  // d = 32..63
    kS0 += 64*HD_; kS1 += 64*HD_;
    vS0 += 64;     vS1 += 64;
  };

  const int ksw = (l15 & 7) << 4;
  const int ksr = (lg >> 1) ^ ((l15 >> 1) & 1);   // V read-side ks-XOR

  auto do_chunk = [&](int cur, bool domask, bool dostage) {
    const char* Kt = (const char*)(kbase + cur*1024);
    const char* Vv = (const char*)(vbase + cur*1024);

    // K frags (this wave's 16 keys), A-operand, shared across all 4 q-tiles
    bf16x8 kf0 = *(const bf16x8*)(Kt + l15*128 + ((lg*16)      ^ ksw));
    bf16x8 kf1 = *(const bf16x8*)(Kt + l15*128 + ((64 + lg*16) ^ ksw));
    // V frags: vb[dt] = Vt[d=dt*16+l15][k = wid*16 + lg*4 .. +3]
    s16x4 vb[4];
    #pragma unroll
    for (int dt=0;dt<4;dt++) {
      int row32 = (dt&1)*16 + l15;
      vb[dt] = *(const s16x4*)(Vv + (dt>>1)*1024 + row32*32 + ksr*16 + (lg&1)*8);
    }

    asm volatile("s_waitcnt lgkmcnt(0)" ::: "memory");   // frags in VGPRs
    __builtin_amdgcn_sched_barrier(0);                   // rule #18
    if (dostage) stage(cur);                             // safe: buffer drained

    // QK^T swapped: st[j]: k-local = wid*16+lg*4+r, q = q0+j*16+l15
    f32x4 st[4];
    __builtin_amdgcn_s_setprio(1);
    #pragma unroll
    for (int j=0;j<4;j++) {
      f32x4 z = f32x4{0.f,0.f,0.f,0.f};
      z = __builtin_amdgcn_mfma_f32_16x16x32_bf16(kf0, qf0[j], z, 0,0,0);
      z = __builtin_amdgcn_mfma_f32_16x16x32_bf16(kf1, qf1[j], z, 0,0,0);
      st[j] = z;
    }
    __builtin_amdgcn_s_setprio(0);

    if (domask) {   // diagonal chunk: wave-local constants
      #pragma unroll
      for (int j=0;j<4;j++)
        #pragma unroll
        for (int r=0;r<4;r++)
          if (wid*16 + lg*4 + r > j*16 + l15) st[j][r] = -INFINITY;
    }

    // P = exp2(score); in-lane pack (S^T C-layout == 16x16x16 A-layout)
    s16x4 pa[4];
    #pragma unroll
    for (int j=0;j<4;j++) {
      float p0 = exp2f(st[j][0]);
      float p1 = exp2f(st[j][1]);
      float p2 = exp2f(st[j][2]);
      float p3 = exp2f(st[j][3]);
      uint2 u;
      u.x = cvt_pk_bf16(p0, p1);
      u.y = cvt_pk_bf16(p2, p3);
      pa[j] = __builtin_bit_cast(s16x4, u);
    }

    __builtin_amdgcn_s_setprio(1);
    #pragma unroll
    for (int j=0;j<4;j++)
      accl[j] = __builtin_amdgcn_mfma_f32_16x16x16bf16_1k(pa[j], ones, accl[j], 0,0,0);
    #pragma unroll
    for (int j=0;j<4;j++)
      #pragma unroll
      for (int dt=0;dt<4;dt++)
        o[j][dt] = __builtin_amdgcn_mfma_f32_16x16x16bf16_1k(pa[j], vb[dt], o[j][dt], 0,0,0);
    __builtin_amdgcn_s_setprio(0);
  };

  stage(0);
  if (nchunk > 1) stage(1);

  int cur = 0;
  for (int ch=0; ch<nchunk-1; ++ch) {
    asm volatile("s_waitcnt vmcnt(4)" ::: "memory");   // chunk ch landed; ch+1 in flight
    __builtin_amdgcn_sched_barrier(0);
    do_chunk(cur, false, ch+2 < nchunk);
    cur ^= 1;
  }
  asm volatile("s_waitcnt vmcnt(0)" ::: "memory");     // last chunk landed
  __builtin_amdgcn_sched_barrier(0);
  do_chunk(cur, true, false);

  // ---- once-per-block additive merge across the 4 waves (LDS tree) ----
  float* bufA = (float*)&SMEM[0][0];   // 16 KB = [64][64] f32
  float* bufB = (float*)&SMEM[2][0];
  __syncthreads();   // all waves done with their K/V regions

  if (wid & 1) {     // round 1: w1 -> bufA, w3 -> bufB
    float* dst = (wid == 1) ? bufA : bufB;
    #pragma unroll
    for (int j=0;j<4;j++) {
      #pragma unroll
      for (int dt=0;dt<4;dt++)
        #pragma unroll
        for (int r=0;r<4;r++)
          dst[(j*16 + lg*4 + r)*64 + dt*16 + l15] = o[j][dt][r];
      if (l15 == 0)
        #pragma unroll
        for (int r=0;r<4;r++) LS[wid>>1][j*16 + lg*4 + r] = accl[j][r];
    }
  }
  __syncthreads();
  if (!(wid & 1)) {  // w0 += bufA/LS0, w2 += bufB/LS1
    float* src = (wid == 0) ? bufA : bufB;
    #pragma unroll
    for (int j=0;j<4;j++) {
      #pragma unroll
      for (int dt=0;dt<4;dt++)
        #pragma unroll
        for (int r=0;r<4;r++)
          o[j][dt][r] += src[(j*16 + lg*4 + r)*64 + dt*16 + l15];
      #pragma unroll
      for (int r=0;r<4;r++) accl[j][r] += LS[wid>>1][j*16 + lg*4 + r];
    }
  }
  __syncthreads();
  if (wid == 2) {    // round 2: w2 -> bufA
    #pragma unroll
    for (int j=0;j<4;j++) {
      #pragma unroll
      for (int dt=0;dt<4;dt++)
        #pragma unroll
        for (int r=0;r<4;r++)
          bufA[(j*16 + lg*4 + r)*64 + dt*16 + l15] = o[j][dt][r];
      if (l15 == 0)
        #pragma unroll
        for (int r=0;r<4;r++) LS[0][j*16 + lg*4 + r] = accl[j][r];
    }
  }
  __syncthreads();
  if (wid == 0) {    // final sum, normalize, store
    #pragma unroll
    for (int j=0;j<4;j++) {
      #pragma unroll
      for (int dt=0;dt<4;dt++)
        #pragma unroll
        for (int r=0;r<4;r++)
          o[j][dt][r] += bufA[(j*16 + lg*4 + r)*64 + dt*16 + l15];
      #pragma unroll
      for (int r=0;r<4;r++) accl[j][r] += LS[0][j*16 + lg*4 + r];
      float lr[4];
      #pragma unroll
      for (int r=0;r<4;r++) lr[r] = 1.f / accl[j][r];
      #pragma unroll
      for (int dt=0;dt<4;dt++)
        #pragma unroll
        for (int r=0;r<4;r++) {
          size_t row = (size_t)(b*S_ + q0 + j*16 + lg*4 + r);
          ctx[row*D_ + h*HD_ + dt*16 + l15] = f2bf(o[j][dt][r] * lr[r]);
        }
    }
  }
}

// ---------- K3: output projection GEMM + bias (bf16 -> fp32 out) ----------
__global__ __launch_bounds__(256,3) void gemm_out_kernel(
    const unsigned short* __restrict__ ctx, const unsigned short* __restrict__ WtO,
    const float* __restrict__ bo, float* __restrict__ out) {
  __shared__ __align__(16) unsigned short As[128*64];
  __shared__ __align__(16) unsigned short Bs[128*64];
  const int m0 = blockIdx.y*128, n0 = blockIdx.x*128;
  const int t = threadIdx.x, lane = t & 63, wid = t >> 6;
  const int wr = (wid>>1)*64, wc = (wid&1)*64;
  const int l15 = lane & 15, lg = lane >> 4;
  const unsigned short* Ab = ctx + (size_t)m0 * D_;
  const unsigned short* Bb = WtO + (size_t)n0 * D_;

  f32x4 acc[4][4];
  #pragma unroll
  for (int m=0;m<4;m++)
    #pragma unroll
    for (int n=0;n<4;n++) acc[m][n] = f32x4{0.f,0.f,0.f,0.f};

  GEMM_K_LOOP(Ab, Bb)

  #pragma unroll
  for (int n=0;n<4;n++) {
    float bias = bo[n0 + wc + n*16 + l15];
    #pragma unroll
    for (int m=0;m<4;m++)
      #pragma unroll
      for (int r=0;r<4;r++) {
        int gm = m0 + wr + m*16 + lg*4 + r;
        int gn = n0 + wc + n*16 + l15;
        out[(size_t)gm*D_ + gn] = acc[m][n][r] + bias;
      }
  }
}

extern "C" void kernel_launch(void* const* d_in, const int* in_sizes, int n_in,
                              void* d_out, int out_size, void* d_ws, size_t ws_size,
                              hipStream_t stream) {
  (void)in_sizes; (void)n_in; (void)out_size; (void)ws_size;
  const float* x  = (const float*)d_in[0];
  const float* Wq = (const float*)d_in[1];
  const float* Wk = (const float*)d_in[2];
  const float* Wv = (const float*)d_in[3];
  const float* Wo = (const float*)d_in[4];
  const float* bo = (const float*)d_in[5];
  float* out = (float*)d_out;

  unsigned short* wt  = (unsigned short*)d_ws;            // 4 * D*D bf16 (transposed weights)
  unsigned short* Qb  = wt  + (size_t)4*D_*D_;            // [B,H,S,HD] (pre-scaled by log2e/8)
  unsigned short* Kb  = Qb  + (size_t)M_*D_;              // [B,H,S,HD]
  unsigned short* Vtb = Kb  + (size_t)M_*D_;              // [B,H,HD,S]
  unsigned short* ctb = Vtb + (size_t)M_*D_;              // [B,S,D]
  unsigned short* xbb = ctb + (size_t)M_*D_;              // [M,D] bf16 x

  xcvt_kernel<<<dim3(M_*D_/(256*8)), 256, 0, stream>>>(x, xbb);
  wtrans_kernel<<<dim3(32,32,4), dim3(32,8), 0, stream>>>(Wq, Wk, Wv, Wo, wt);
  gemm_qkv_kernel<<<dim3(8,32,3), 256, 0, stream>>>(xbb, wt, Qb, Kb, Vtb);
  attn_kernel<<<dim3(1024), 256, 0, stream>>>(Qb, Kb, Vtb, ctb);
  gemm_out_kernel<<<dim3(8,32), 256, 0, stream>>>(ctb, wt + (size_t)3*D_*D_, bo, out);
}